// Round 14
// baseline (234.502 us; speedup 1.0000x reference)
//
#include <hip/hip_runtime.h>

// Problem constants (match reference)
#define BATCHN 32
#define NCELL  4096
#define BN     (BATCHN * NCELL)

// Round 14: two-tile ILP pairing.
// Fit (R10/R12/R13): OH~3us/dispatch, per-step ~8.3 cyc/instr vs 2-cyc
// issue + ~4-5cyc dep latency => wave is dependency-bound at ~1-wide ILP.
// R8 showed TLP-with-redundancy just adds issue. Untested lever: ILP at
// unchanged wave count — each wave advances TWO independent tiles packed
// in the .x/.y of every v2f op (evals/fluxes/updates pair for free; only
// DPP exchange and stores are per-tile).
//   2048 tiles = 64 chunks x 32 rows, OWN=64, HALO=64, CELLS=192 (3/lane)
//   1024 waves (1/SIMD), KSTEP=60, D=10 (proven dispatch structure).
constexpr int TPL    = 3;                  // cells per lane per tile
constexpr int HALO   = 64;
constexpr int OWN    = 64;
constexpr int CELLS  = 64 * TPL;           // 192 = OWN + 2*HALO
constexpr int KSTEP  = 60;                 // steps per launch (< HALO)
constexpr int CHUNKS = NCELL / OWN;        // 64
constexpr int NPAIR  = CHUNKS / 2;         // 32 tile-pairs per row

typedef float v2f __attribute__((ext_vector_type(2)));

// hf = 0.5*f_real(u), ha = 0.5*|f_real'(u)| — monomial expansion, 0.5
// pre-folded (verified vs reference at u=1: f=1,f'=0; u=0.5: f=0.710286,
// f'=1.085938). Flux uses 0.5*max(a,b) == max(0.5a,0.5b) exactly.
// .x component = tile A, .y = tile B (independent -> 2-wide ILP).
__device__ __forceinline__ void eval2(v2f u, v2f& hf, v2f& ha) {
    v2f u2 = u * u;
    v2f u3 = u2 * u;
    v2f p1 = u * 0.3125f + 0.75f;
    v2f A  = u * p1;                               // 0.75u + 0.3125u^2
    v2f p2 = u * 0.625f + (-1.0833333333333333f);  // -13/12 + 0.625u
    v2f B  = u3 * p2 + A;
    v2f u6 = u3 * u3;
    hf = u6 * (-0.10416666666666667f) + B;         // -5/48 u^6
    v2f p3 = u * 0.625f + 0.75f;
    v2f p4 = u * 2.5f + (-3.25f);
    v2f C  = u2 * p4 + p3;                         // 0.75+0.625u-3.25u^2+2.5u^3
    v2f u5 = u2 * u3;
    v2f hd = u5 * (-0.625f) + C;
    ha.x = fabsf(hd.x);
    ha.y = fabsf(hd.y);
}

__device__ __forceinline__ v2f vmax2(v2f a, v2f b) {
    v2f r;
    r.x = fmaxf(a.x, b.x);
    r.y = fmaxf(a.y, b.y);
    return r;
}

// lane i <- lane i-1 (edge lane keeps self): DPP WAVE_SHR:1 = 0x138
__device__ __forceinline__ float dpp_left(float v) {
    int i = __float_as_int(v);
    return __int_as_float(
        __builtin_amdgcn_update_dpp(i, i, 0x138, 0xF, 0xF, false));
}
// lane i <- lane i+1 (edge lane keeps self): DPP WAVE_SHL:1 = 0x130
__device__ __forceinline__ float dpp_right(float v) {
    int i = __float_as_int(v);
    return __int_as_float(
        __builtin_amdgcn_update_dpp(i, i, 0x130, 0xF, 0xF, false));
}

__global__ __launch_bounds__(64) void lf_wave(const float* __restrict__ in_state,
                                              float* __restrict__ out,
                                              int s0, int nsteps) {
    const int lane  = threadIdx.x;            // one wave per block
    const int wid   = blockIdx.x;
    const int cpair = wid & (NPAIR - 1);
    const int row   = wid >> 5;               // NPAIR == 32
    const int chunkA = 2 * cpair;
    const int chunkB = 2 * cpair + 1;
    const int gbA   = chunkA * OWN - HALO;    // local c -> global gbA + c
    const int gbB   = chunkB * OWN - HALO;
    const int c0    = lane * TPL;

    const float dtdx = (float)(0.0009 / (10.0 / 4096.0));
    const v2f dtdxv = { dtdx, dtdx };

    // load both tiles' 3 cells/lane (clamped at physical edges)
    v2f U0, U1, U2;
    {
        const float* ip = in_state + (size_t)row * NCELL;
        int gA0 = min(max(gbA + c0 + 0, 0), NCELL - 1);
        int gA1 = min(max(gbA + c0 + 1, 0), NCELL - 1);
        int gA2 = min(max(gbA + c0 + 2, 0), NCELL - 1);
        int gB0 = min(max(gbB + c0 + 0, 0), NCELL - 1);
        int gB1 = min(max(gbB + c0 + 1, 0), NCELL - 1);
        int gB2 = min(max(gbB + c0 + 2, 0), NCELL - 1);
        U0.x = ip[gA0]; U0.y = ip[gB0];
        U1.x = ip[gA1]; U1.y = ip[gB1];
        U2.x = ip[gA2]; U2.y = ip[gB2];
    }

    // ownership of local cells [64,128): lane l covers 3l..3l+2
    //  j0 owned for lanes 22..42 (cells 66..126)
    //  j1 owned for lanes 21..42 (cells 64..127)
    //  j2 owned for lanes 21..41 (cells 65..125)
    const bool st0 = (lane >= 22) && (lane <= 42);
    const bool st1 = (lane >= 21) && (lane <= 42);
    const bool st2 = (lane >= 21) && (lane <= 41);
    // BCs: global cell 0 = tileA of cpair0, local 64 = lane21 j1;
    //      global cell 4095 = tileB of cpair31, local 127 = lane42 j1.
    const bool bcA = (cpair == 0) && (lane == 21);
    const bool bcB = (cpair == NPAIR - 1) && (lane == 42);

    float* opA = out + (size_t)(s0 + 1) * BN + (size_t)row * NCELL + (gbA + c0);
    float* opB = out + (size_t)(s0 + 1) * BN + (size_t)row * NCELL + (gbB + c0);

    // dispatch 0: write plane 0 (= init), replacing the d2d memcpy
    if (s0 == 0) {
        if (st0) { opA[0 - BN] = U0.x; opB[0 - BN] = U0.y; }
        if (st1) { opA[1 - BN] = U1.x; opB[1 - BN] = U1.y; }
        if (st2) { opA[2 - BN] = U2.x; opB[2 - BN] = U2.y; }
    }

    #pragma unroll 4
    for (int t = 0; t < nsteps; ++t) {
        v2f HF0, HA0, HF1, HA1, HF2, HA2;
        eval2(U0, HF0, HA0);
        eval2(U1, HF1, HA1);
        eval2(U2, HF2, HA2);

        // per-tile halo exchange via DPP (VALU pipe)
        v2f ul, hfl, hal, ur, hfr, har;
        ul.x  = dpp_left(U2.x);   ul.y  = dpp_left(U2.y);
        hfl.x = dpp_left(HF2.x);  hfl.y = dpp_left(HF2.y);
        hal.x = dpp_left(HA2.x);  hal.y = dpp_left(HA2.y);
        ur.x  = dpp_right(U0.x);  ur.y  = dpp_right(U0.y);
        hfr.x = dpp_right(HF0.x); hfr.y = dpp_right(HF0.y);
        har.x = dpp_right(HA0.x); har.y = dpp_right(HA0.y);

        // 4 interface fluxes per tile, packed (0.5 pre-folded into hf/ha)
        v2f fhL = (hfl + HF0) - vmax2(hal, HA0) * (U0 - ul);
        v2f f01 = (HF0 + HF1) - vmax2(HA0, HA1) * (U1 - U0);
        v2f f12 = (HF1 + HF2) - vmax2(HA1, HA2) * (U2 - U1);
        v2f fhR = (HF2 + hfr) - vmax2(HA2, har) * (ur - U2);

        U0 = U0 - dtdxv * (f01 - fhL);
        U1 = U1 - dtdxv * (f12 - f01);
        U2 = U2 - dtdxv * (fhR - f12);

        // outflow BCs (firewall against halo garbage)
        if (bcA) U1.x = U2.x;   // u[0]    = u[1]
        if (bcB) U1.y = U0.y;   // u[N-1]  = u[N-2]

        // store owned cells of this plane (scalar, masked per j)
        if (st0) { opA[0] = U0.x; opB[0] = U0.y; }
        if (st1) { opA[1] = U1.x; opB[1] = U1.y; }
        if (st2) { opA[2] = U2.x; opB[2] = U2.y; }
        opA += BN;
        opB += BN;
    }
}

extern "C" void kernel_launch(void* const* d_in, const int* in_sizes, int n_in,
                              void* d_out, int out_size, void* d_ws, size_t ws_size,
                              hipStream_t stream) {
    const float* init = (const float*)d_in[0];
    float* out = (float*)d_out;

    const int total = out_size / BN - 1;

    const int nblocks = NPAIR * BATCHN;     // 1024 waves, 1/SIMD chip-wide
    for (int s = 0; s < total; s += KSTEP) {
        int ns = (total - s) < KSTEP ? (total - s) : KSTEP;
        const float* src = (s == 0) ? init : out + (size_t)s * BN;
        lf_wave<<<nblocks, 64, 0, stream>>>(src, out, s, ns);
    }
}

// Round 15
// 137.944 us; speedup vs baseline: 1.7000x; 1.7000x over previous
//
#include <hip/hip_runtime.h>

// Problem constants (match reference)
#define BATCHN 32
#define NCELL  4096
#define BN     (BATCHN * NCELL)

// Round 15: issue-count minimization via even/odd packing.
// Model (fits R7/R8/R10/R12-R14 within ~5%): dur = 600*(issue cyc/step)
// + D*3us. Pure issue-bound; latency irrelevant (TLP/store-depth/barrier
// all neutral); R14's two-tile "ILP" was a non-test (packed halves share
// one instruction). Geometry fixed at the flat-curve optimum (CPL=4,
// OWN=128, HALO=64, KSTEP=60, D=10, 1024 waves = 1/SIMD). Cuts:
//  - even/odd layout E={u0,u2}, O={u1,u3}: interfaces {i1,i3},{i2,i4}
//    and both updates become whole-register v_pk ops (no op_sel shuffles)
//  - signed hd kept; |src| modifiers applied at the 3 max sites (free)
//  - stores grouped 4 per exec region
// Owned-cell expression trees value-identical to R10/R13 -> absmax
// expected unchanged (0.00390625).
constexpr int OWN    = 128;
constexpr int HALO   = 64;
constexpr int CPL    = 4;                  // cells per lane
constexpr int KSTEP  = 60;                 // steps per launch (< HALO)
constexpr int CHUNKS = NCELL / OWN;        // 32

typedef float v2f __attribute__((ext_vector_type(2)));

// hf = 0.5*f_real(u) (monomial, 0.5 pre-folded), hd = 0.5*f_real'(u)
// SIGNED (abs applied via |modifier| at max sites). Coefficients verified
// vs reference at u=1 (f=1,f'=0) and u=0.5 (f=0.710286, f'=1.085938).
__device__ __forceinline__ void eval2(v2f u, v2f& hf, v2f& hd) {
    v2f u2 = u * u;
    v2f u3 = u2 * u;
    v2f p1 = u * 0.3125f + 0.75f;
    v2f A  = u * p1;                               // 0.75u + 0.3125u^2
    v2f p2 = u * 0.625f + (-1.0833333333333333f);  // -13/12 + 0.625u
    v2f B  = u3 * p2 + A;
    v2f u6 = u3 * u3;
    hf = u6 * (-0.10416666666666667f) + B;         // -5/48 u^6
    v2f p3 = u * 0.625f + 0.75f;
    v2f p4 = u * 2.5f + (-3.25f);
    v2f C  = u2 * p4 + p3;                         // 0.75+0.625u-3.25u^2+2.5u^3
    v2f u5 = u2 * u3;
    hd = u5 * (-0.625f) + C;                       // signed 0.5*f'
}

__device__ __forceinline__ v2f vmaxabs2(v2f a, v2f b) {
    v2f r;
    r.x = fmaxf(fabsf(a.x), fabsf(b.x));   // |src| modifiers on v_pk_max
    r.y = fmaxf(fabsf(a.y), fabsf(b.y));
    return r;
}

// lane i <- lane i-1 (edge lane keeps self): DPP WAVE_SHR:1 = 0x138
__device__ __forceinline__ float dpp_left(float v) {
    int i = __float_as_int(v);
    return __int_as_float(
        __builtin_amdgcn_update_dpp(i, i, 0x138, 0xF, 0xF, false));
}
// lane i <- lane i+1 (edge lane keeps self): DPP WAVE_SHL:1 = 0x130
__device__ __forceinline__ float dpp_right(float v) {
    int i = __float_as_int(v);
    return __int_as_float(
        __builtin_amdgcn_update_dpp(i, i, 0x130, 0xF, 0xF, false));
}

// One LF step on 4 cells/lane in even/odd layout E={u0,u2}, O={u1,u3}.
__device__ __forceinline__ void lf_step(v2f& E, v2f& O, float b[CPL],
                                        bool bcL, bool bcR, float dtdx) {
    v2f hfE, hdE, hfO, hdO;
    eval2(E, hfE, hdE);
    eval2(O, hfO, hdO);

    // halo exchange via DPP (VALU pipe): need left's cell3 (O.y) and
    // right's cell0 (E.x) families
    float ul  = dpp_left(O.y);
    float hfl = dpp_left(hfO.y);
    float hdl = dpp_left(hdO.y);
    float ur  = dpp_right(E.x);
    float hfr = dpp_right(hfE.x);
    float hdr = dpp_right(hdE.x);

    // interfaces i1(c0,c1), i3(c2,c3): fully packed, whole registers
    v2f F13 = (hfE + hfO) - vmaxabs2(hdE, hdO) * (O - E);
    // interfaces i2(c1,c2), i4(c3, right c0): R-halves {E.y, r}
    v2f Rhf, Ru, Rhd;
    Rhf.x = hfE.y; Rhf.y = hfr;
    Ru.x  = E.y;   Ru.y  = ur;
    Rhd.x = hdE.y; Rhd.y = hdr;
    v2f F24 = (hfO + Rhf) - vmaxabs2(hdO, Rhd) * (Ru - O);
    // interface i0(left c3, c0): scalar
    float i0 = (hfl + hfE.x)
             - fmaxf(fabsf(hdl), fabsf(hdE.x)) * (E.x - ul);

    // updates: nE = E - d*(F13 - {i0, i2}), nO = O - d*(F24 - F13)
    v2f G;
    G.x = i0; G.y = F24.x;
    v2f nE = E - dtdx * (F13 - G);
    v2f nO = O - dtdx * (F24 - F13);

    // outflow BCs: u[0]=u[1] (cell0 <- cell1), u[N-1]=u[N-2] (cell3 <- cell2)
    if (bcL) nE.x = nO.x;
    if (bcR) nO.y = nE.y;

    b[0] = nE.x; b[1] = nO.x; b[2] = nE.y; b[3] = nO.y;
    E = nE;
    O = nO;
}

__global__ __launch_bounds__(64) void lf_wave(const float* __restrict__ in_state,
                                              float* __restrict__ out,
                                              int s0, int nsteps) {
    const int lane  = threadIdx.x;          // one wave per block
    const int wid   = blockIdx.x;
    const int chunk = wid & (CHUNKS - 1);
    const int row   = wid >> 5;             // CHUNKS == 32
    const int gbase = chunk * OWN - HALO;
    const int c0    = lane * CPL;

    const float dtdx = (float)(0.0009 / (10.0 / 4096.0));

    float uin[CPL];
    {
        const float* ip = in_state + (size_t)row * NCELL;
        #pragma unroll
        for (int j = 0; j < CPL; ++j) {
            int g = gbase + c0 + j;
            g = min(max(g, 0), NCELL - 1);
            uin[j] = ip[g];
        }
    }
    v2f E, O;
    E.x = uin[0]; E.y = uin[2];
    O.x = uin[1]; O.y = uin[3];

    // owned cells [64,192) -> lanes 16..47 (all 4 cells contiguous)
    const bool owned = (lane >= 16) && (lane < 48);
    const bool bcL = (chunk == 0) && (lane == 16);            // global cell 0
    const bool bcR = (chunk == CHUNKS - 1) && (lane == 47);   // global cell N-1

    float* op = out + (size_t)(s0 + 1) * BN + (size_t)row * NCELL + (gbase + c0);

    // dispatch 0: write plane 0 (= init), replacing the d2d memcpy
    if (s0 == 0 && owned) {
        *(float4*)(op - BN) = make_float4(uin[0], uin[1], uin[2], uin[3]);
    }

    int t = 0;
    // groups of 4 steps, stores batched per group in one exec region
    for (; t + 4 <= nsteps; t += 4) {
        float b0[CPL], b1[CPL], b2[CPL], b3[CPL];
        lf_step(E, O, b0, bcL, bcR, dtdx);
        lf_step(E, O, b1, bcL, bcR, dtdx);
        lf_step(E, O, b2, bcL, bcR, dtdx);
        lf_step(E, O, b3, bcL, bcR, dtdx);
        if (owned) {
            *(float4*)(op)            = make_float4(b0[0], b0[1], b0[2], b0[3]);
            *(float4*)(op + BN)       = make_float4(b1[0], b1[1], b1[2], b1[3]);
            *(float4*)(op + 2 * BN)   = make_float4(b2[0], b2[1], b2[2], b2[3]);
            *(float4*)(op + 3 * BN)   = make_float4(b3[0], b3[1], b3[2], b3[3]);
        }
        op += 4 * BN;
    }
    // tail (not hit for nsteps=60, kept for robustness)
    for (; t < nsteps; ++t) {
        float b[CPL];
        lf_step(E, O, b, bcL, bcR, dtdx);
        if (owned) *(float4*)op = make_float4(b[0], b[1], b[2], b[3]);
        op += BN;
    }
}

extern "C" void kernel_launch(void* const* d_in, const int* in_sizes, int n_in,
                              void* d_out, int out_size, void* d_ws, size_t ws_size,
                              hipStream_t stream) {
    const float* init = (const float*)d_in[0];
    float* out = (float*)d_out;

    const int total = out_size / BN - 1;

    const int nblocks = CHUNKS * BATCHN;    // 1024 waves, 1/SIMD chip-wide
    for (int s = 0; s < total; s += KSTEP) {
        int ns = (total - s) < KSTEP ? (total - s) : KSTEP;
        const float* src = (s == 0) ? init : out + (size_t)s * BN;
        lf_wave<<<nblocks, 64, 0, stream>>>(src, out, s, ns);
    }
}

// Round 16
// 114.163 us; speedup vs baseline: 2.0541x; 1.2083x over previous
//
#include <hip/hip_runtime.h>

// Problem constants (match reference)
#define BATCHN 32
#define NCELL  4096
#define BN     (BATCHN * NCELL)

// Round 16: Horner evals + flux-reuse exchange (4 DPP total).
// Model (5 rounds confirmed): dur = 600*(instr/step)*~8cyc + D*3us OH.
// Cuts vs R15 (~57 -> ~45 instr/step):
//  - eval2 via Horner w/ shared u^2: 13 -> 10 packed ops
//  - exchange: 3 right-DPPs only; left-edge flux i0 = dpp_left(F24.y),
//    bit-identical to the old 3-left-DPP + 4-op scalar path for interior
//    lanes (adds commuted, max symmetric, same signed difference); lane-0
//    halo garbage differs but is firewalled (owned region untouched).
// Geometry unchanged: CPL=4, OWN=128, HALO=64, KSTEP=60, D=10, 1024 waves.
constexpr int OWN    = 128;
constexpr int HALO   = 64;
constexpr int CPL    = 4;                  // cells per lane
constexpr int KSTEP  = 60;                 // steps per launch (< HALO)
constexpr int CHUNKS = NCELL / OWN;        // 32

typedef float v2f __attribute__((ext_vector_type(2)));

// hf = 0.5*f_real(u), hd = 0.5*f_real'(u) (signed; |.| applied at max).
// Horner forms (coefficients verified vs reference at u=1: f=1,f'=0 and
// u=0.5: f=0.710286, f'=1.085938):
//  hf = u*(0.75 + u*(0.3125 + u*(-13/12 + u*(0.625 - (5/48)u^2))))
//  hd = 0.75 + u*(0.625 + u*(-3.25 + u*(2.5 - 0.625u^2)))
__device__ __forceinline__ void eval2(v2f u, v2f& hf, v2f& hd) {
    v2f u2 = u * u;
    v2f s0 = u2 * (-0.10416666666666667f) + 0.625f;
    v2f s1 = u * s0 + (-1.0833333333333333f);
    v2f s2 = u * s1 + 0.3125f;
    v2f s3 = u * s2 + 0.75f;
    hf = u * s3;
    v2f t0 = u2 * (-0.625f) + 2.5f;
    v2f t1 = u * t0 + (-3.25f);
    v2f t2 = u * t1 + 0.625f;
    hd = u * t2 + 0.75f;
}

__device__ __forceinline__ v2f vmaxabs2(v2f a, v2f b) {
    v2f r;
    r.x = fmaxf(fabsf(a.x), fabsf(b.x));   // |src| modifiers, free in VOP3P
    r.y = fmaxf(fabsf(a.y), fabsf(b.y));
    return r;
}

// lane i <- lane i-1 (edge lane keeps self): DPP WAVE_SHR:1 = 0x138
__device__ __forceinline__ float dpp_left(float v) {
    int i = __float_as_int(v);
    return __int_as_float(
        __builtin_amdgcn_update_dpp(i, i, 0x138, 0xF, 0xF, false));
}
// lane i <- lane i+1 (edge lane keeps self): DPP WAVE_SHL:1 = 0x130
__device__ __forceinline__ float dpp_right(float v) {
    int i = __float_as_int(v);
    return __int_as_float(
        __builtin_amdgcn_update_dpp(i, i, 0x130, 0xF, 0xF, false));
}

// One LF step on 4 cells/lane in even/odd layout E={u0,u2}, O={u1,u3}.
__device__ __forceinline__ void lf_step(v2f& E, v2f& O, float b[CPL],
                                        bool bcL, bool bcR, float dtdx) {
    v2f hfE, hdE, hfO, hdO;
    eval2(E, hfE, hdE);
    eval2(O, hfO, hdO);

    // exchange: only right neighbor's c0 family (3 DPP)
    float ur  = dpp_right(E.x);
    float hfr = dpp_right(hfE.x);
    float hdr = dpp_right(hdE.x);

    // interfaces i1(c0,c1), i3(c2,c3): fully packed
    v2f F13 = (hfE + hfO) - vmaxabs2(hdE, hdO) * (O - E);
    // interfaces i2(c1,c2), i4(c3, right c0): R-halves {E.y, r}
    v2f Rhf, Ru, Rhd;
    Rhf.x = hfE.y; Rhf.y = hfr;
    Ru.x  = E.y;   Ru.y  = ur;
    Rhd.x = hdE.y; Rhd.y = hdr;
    v2f F24 = (hfO + Rhf) - vmaxabs2(hdO, Rhd) * (Ru - O);

    // left-edge flux = left neighbor's right-edge flux (bit-identical to
    // computing it from exchanged left values; lane 0 garbage firewalled)
    float i0 = dpp_left(F24.y);

    v2f G;
    G.x = i0; G.y = F24.x;
    v2f nE = E - dtdx * (F13 - G);
    v2f nO = O - dtdx * (F24 - F13);

    // outflow BCs: u[0]=u[1] (cell0 <- cell1), u[N-1]=u[N-2] (cell3 <- cell2)
    if (bcL) nE.x = nO.x;
    if (bcR) nO.y = nE.y;

    b[0] = nE.x; b[1] = nO.x; b[2] = nE.y; b[3] = nO.y;
    E = nE;
    O = nO;
}

__global__ __launch_bounds__(64) void lf_wave(const float* __restrict__ in_state,
                                              float* __restrict__ out,
                                              int s0, int nsteps) {
    const int lane  = threadIdx.x;          // one wave per block
    const int wid   = blockIdx.x;
    const int chunk = wid & (CHUNKS - 1);
    const int row   = wid >> 5;             // CHUNKS == 32
    const int gbase = chunk * OWN - HALO;
    const int c0    = lane * CPL;

    const float dtdx = (float)(0.0009 / (10.0 / 4096.0));

    float uin[CPL];
    {
        const float* ip = in_state + (size_t)row * NCELL;
        #pragma unroll
        for (int j = 0; j < CPL; ++j) {
            int g = gbase + c0 + j;
            g = min(max(g, 0), NCELL - 1);
            uin[j] = ip[g];
        }
    }
    v2f E, O;
    E.x = uin[0]; E.y = uin[2];
    O.x = uin[1]; O.y = uin[3];

    // owned cells [64,192) -> lanes 16..47 (all 4 cells contiguous)
    const bool owned = (lane >= 16) && (lane < 48);
    const bool bcL = (chunk == 0) && (lane == 16);            // global cell 0
    const bool bcR = (chunk == CHUNKS - 1) && (lane == 47);   // global cell N-1

    float* op = out + (size_t)(s0 + 1) * BN + (size_t)row * NCELL + (gbase + c0);

    // dispatch 0: write plane 0 (= init), replacing the d2d memcpy
    if (s0 == 0 && owned) {
        *(float4*)(op - BN) = make_float4(uin[0], uin[1], uin[2], uin[3]);
    }

    int t = 0;
    // groups of 4 steps, stores batched per group in one exec region
    for (; t + 4 <= nsteps; t += 4) {
        float b0[CPL], b1[CPL], b2[CPL], b3[CPL];
        lf_step(E, O, b0, bcL, bcR, dtdx);
        lf_step(E, O, b1, bcL, bcR, dtdx);
        lf_step(E, O, b2, bcL, bcR, dtdx);
        lf_step(E, O, b3, bcL, bcR, dtdx);
        if (owned) {
            *(float4*)(op)            = make_float4(b0[0], b0[1], b0[2], b0[3]);
            *(float4*)(op + BN)       = make_float4(b1[0], b1[1], b1[2], b1[3]);
            *(float4*)(op + 2 * BN)   = make_float4(b2[0], b2[1], b2[2], b2[3]);
            *(float4*)(op + 3 * BN)   = make_float4(b3[0], b3[1], b3[2], b3[3]);
        }
        op += 4 * BN;
    }
    // tail (not hit for nsteps=60, kept for robustness)
    for (; t < nsteps; ++t) {
        float b[CPL];
        lf_step(E, O, b, bcL, bcR, dtdx);
        if (owned) *(float4*)op = make_float4(b[0], b[1], b[2], b[3]);
        op += BN;
    }
}

extern "C" void kernel_launch(void* const* d_in, const int* in_sizes, int n_in,
                              void* d_out, int out_size, void* d_ws, size_t ws_size,
                              hipStream_t stream) {
    const float* init = (const float*)d_in[0];
    float* out = (float*)d_out;

    const int total = out_size / BN - 1;

    const int nblocks = CHUNKS * BATCHN;    // 1024 waves, 1/SIMD chip-wide
    for (int s = 0; s < total; s += KSTEP) {
        int ns = (total - s) < KSTEP ? (total - s) : KSTEP;
        const float* src = (s == 0) ? init : out + (size_t)s * BN;
        lf_wave<<<nblocks, 64, 0, stream>>>(src, out, s, ns);
    }
}